// Round 4
// baseline (262.371 us; speedup 1.0000x reference)
//
#include <hip/hip_runtime.h>
#include <hip/hip_bf16.h>
#include <cstdint>
#include <cstddef>

// B=4, T=4096, C=1024, d=64 causal self-attention head.
// R4: proj_gemm restaged through LDS via global_load_lds (async, width 16,
// double-buffered 64x64-f32 tiles, XOR-swizzled chunks). flash unchanged
// from R3 (block-cooperative LDS staging, split-KV, fixed-max softmax).

typedef __attribute__((ext_vector_type(8))) short short8;       // 8 x bf16 frag
typedef __attribute__((ext_vector_type(4))) float f32x4;
typedef __attribute__((ext_vector_type(4))) unsigned int uint4v;
typedef __attribute__((ext_vector_type(4))) unsigned short ushort4v;
typedef unsigned short ushort;

#define MFMA16x16x32(A,B,C) __builtin_amdgcn_mfma_f32_16x16x32_bf16((A),(B),(C),0,0,0)

static __device__ __forceinline__ unsigned pack2_bf16(float f0, float f1){
  unsigned u0 = __builtin_bit_cast(unsigned, f0) + 0x8000u;
  unsigned u1 = __builtin_bit_cast(unsigned, f1) + 0x8000u;
  return __builtin_amdgcn_perm(u1, u0, 0x07060302u);
}
static __device__ __forceinline__ unsigned short bf16u(float f){
  return (unsigned short)((__builtin_bit_cast(unsigned, f) + 0x8000u) >> 16);
}
static __device__ __forceinline__ short8 cvt8(f32x4 a, f32x4 b){
  union { unsigned u[4]; short8 s; } r;
  r.u[0] = pack2_bf16(a[0], a[1]);
  r.u[1] = pack2_bf16(a[2], a[3]);
  r.u[2] = pack2_bf16(b[0], b[1]);
  r.u[3] = pack2_bf16(b[2], b[3]);
  return r.s;
}
static __device__ __forceinline__ float fast_exp2(float x){
  float r; asm("v_exp_f32 %0, %1" : "=v"(r) : "v"(x)); return r;
}
static __device__ __forceinline__ float fast_rcp(float x){
  float r; asm("v_rcp_f32 %0, %1" : "=v"(r) : "v"(x)); return r;
}
static __device__ __forceinline__ void gl_lds16(const void* g, void* l){
  __builtin_amdgcn_global_load_lds(
      (const __attribute__((address_space(1))) void*)g,
      (__attribute__((address_space(3))) void*)l, 16, 0, 0);
}

// ---------------------------------------------------------------------------
// Kernel 0: pack W fp32 -> bf16 B-fragment layout; also zero out (4MB) + L.
// ---------------------------------------------------------------------------
__global__ __launch_bounds__(256) void pack_w(
    const float* __restrict__ Wq, const float* __restrict__ Wk,
    const float* __restrict__ Wv, unsigned short* __restrict__ Wp,
    float* __restrict__ out, float* __restrict__ Lbuf)
{
  int t = blockIdx.x * 256 + threadIdx.x;      // 256 blocks x 256 = 65536 thr
  if (t < 24576){                               // 3*32*4*64 pack jobs
    int lane = t & 63, nf = (t >> 6) & 3, cc = (t >> 8) & 31, p = t >> 13;
    int qd = lane >> 4, l = lane & 15;
    const float* W = (p == 0) ? Wq : ((p == 1) ? Wk : Wv);
    const float* src = W + (size_t)(cc * 32 + qd * 8) * 64 + nf * 16 + l;
    uint4v u;
    #pragma unroll
    for (int j = 0; j < 4; ++j)
      u[j] = pack2_bf16(src[(2 * j) * 64], src[(2 * j + 1) * 64]);
    *(uint4v*)(Wp + (size_t)t * 8) = u;
  }
  const f32x4 z = (f32x4){0.f, 0.f, 0.f, 0.f};
  f32x4* o4 = (f32x4*)out;
  f32x4* l4 = (f32x4*)Lbuf;
  for (int i = t; i < 262144 + 4096; i += 65536){
    if (i < 262144) o4[i] = z;
    else l4[i - 262144] = z;
  }
}

// ---------------------------------------------------------------------------
// Kernel 1: projections, LDS-staged. grid (256, 3), block 256 (4 waves).
// Block tile: 64 rows x C. Stage: 64 rows x 64 f32 cols = 16 KB, dbuf.
// LDS[row][slot s] (stride 256B, 16 slots of 16B) holds global 16B-chunk
// j = s ^ (row&15)  -> fragment ds_read_b128 is bank-optimal; staging calls
// are contiguous-per-wave (global_load_lds constraint) with swizzle applied
// to the *global* address.
// ---------------------------------------------------------------------------
__global__ __launch_bounds__(256) void proj_gemm(
    const float* __restrict__ Qx, const float* __restrict__ Kx, const float* __restrict__ Vx,
    const float* __restrict__ bqp, const float* __restrict__ bkp, const float* __restrict__ bvp,
    const unsigned short* __restrict__ Wp,
    unsigned short* __restrict__ qb, unsigned short* __restrict__ kb,
    unsigned short* __restrict__ vt)
{
  __shared__ float Xs[2][4096];                 // 2 x 16 KB
  const int tid = threadIdx.x;
  const int lane = tid & 63, wid = tid >> 6;
  const int qd = lane >> 4, l = lane & 15;
  const int p = blockIdx.y;
  const float* X = (p == 0) ? Qx : ((p == 1) ? Kx : Vx);
  const float* bias = (p == 0) ? bqp : ((p == 1) ? bkp : bvp);
  const unsigned short* W = Wp + (size_t)p * 65536;

  const int row0 = blockIdx.x * 64;             // block rows
  const unsigned short* wb = W + (size_t)lane * 8;

  // staging geometry (per wave-instr): lanes cover rows rloc16 = 4*wid + qd
  // within a 16-row call group; slot = l, global chunk j = l ^ rloc16.
  const int rloc16 = 4 * wid + qd;
  const int jsw = l ^ rloc16;
  const float* gsrc = X + (size_t)(row0 + rloc16) * 1024 + jsw * 4;

#define STAGE(BB, ST) do{                                                      \
    const float* g_ = gsrc + (ST) * 64;                                        \
    float* d_ = &Xs[BB][wid * 256];                                            \
    gl_lds16(g_,               d_);                                            \
    gl_lds16(g_ + 16 * 1024,   d_ + 1024);                                     \
    gl_lds16(g_ + 32 * 1024,   d_ + 2048);                                     \
    gl_lds16(g_ + 48 * 1024,   d_ + 3072);                                     \
  } while (0)

  f32x4 acc[4];
  #pragma unroll
  for (int nf = 0; nf < 4; ++nf) acc[nf] = (f32x4){0.f, 0.f, 0.f, 0.f};

  const int rloc = wid * 16 + l;                // fragment row (r&15 == l)
  const float* xrow0 = &Xs[0][rloc * 64];
  const float* xrow1 = &Xs[1][rloc * 64];

  STAGE(0, 0);
  __syncthreads();
  #pragma unroll 2
  for (int st = 0; st < 16; ++st){
    int bb = st & 1;
    if (st + 1 < 16) STAGE(bb ^ 1, st + 1);
    const float* xr = bb ? xrow1 : xrow0;
    #pragma unroll
    for (int kc = 0; kc < 2; ++kc){
      int j0 = kc * 8 + 2 * qd;
      f32x4 al = *(const f32x4*)(xr + ((j0 ^ l) << 2));
      f32x4 ah = *(const f32x4*)(xr + (((j0 + 1) ^ l) << 2));
      const unsigned short* wc = wb + (size_t)(st * 2 + kc) * 2048;
      short8 b0 = *(const short8*)(wc);
      short8 b1 = *(const short8*)(wc + 512);
      short8 b2 = *(const short8*)(wc + 1024);
      short8 b3 = *(const short8*)(wc + 1536);
      short8 a = cvt8(al, ah);
      acc[0] = MFMA16x16x32(a, b0, acc[0]);
      acc[1] = MFMA16x16x32(a, b1, acc[1]);
      acc[2] = MFMA16x16x32(a, b2, acc[2]);
      acc[3] = MFMA16x16x32(a, b3, acc[3]);
    }
    __syncthreads();
  }
#undef STAGE

  const int rw0 = row0 + wid * 16;              // wave's output row base
  if (p == 2){
    int tg = rw0 + qd * 4;
    int b = tg >> 12, tl = tg & 4095;
    #pragma unroll
    for (int nf = 0; nf < 4; ++nf){
      float bb = bias[nf * 16 + l];
      ushort4v pk;
      #pragma unroll
      for (int r = 0; r < 4; ++r) pk[r] = bf16u(acc[nf][r] + bb);
      *(ushort4v*)(vt + ((size_t)b * 64 + nf * 16 + l) * 4096 + tl) = pk;
    }
  } else {
    unsigned short* o = (p == 0) ? qb : kb;
    #pragma unroll
    for (int nf = 0; nf < 4; ++nf){
      float bb = bias[nf * 16 + l];
      #pragma unroll
      for (int r = 0; r < 4; ++r){
        int row = rw0 + qd * 4 + r;
        o[(size_t)row * 64 + nf * 16 + l] = bf16u(acc[nf][r] + bb);
      }
    }
  }
}

// ---------------------------------------------------------------------------
// Kernel 2: split-KV causal flash, block-cooperative LDS staging (as R3).
// ---------------------------------------------------------------------------
#define K1 0.18033688011112042f   // log2(e)/sqrt(64)

__global__ __launch_bounds__(256) void flash_split(
    const ushort* __restrict__ qb, const ushort* __restrict__ kb,
    const ushort* __restrict__ vt, float* __restrict__ out,
    float* __restrict__ Lbuf)
{
  __shared__ ushort Ks[2][4096];      // [buf][kvrow(64) * 64], 8 slots/row, c^(r&7)
  __shared__ ushort Vs[2][4096];      // [buf][d(64) * 64kv], 8 slots/row, c^(d&7)
  __shared__ ushort pbuf[4][16 * 40];

  const int tid = threadIdx.x;
  const int lane = tid & 63, wid = tid >> 6;
  const int qd = lane >> 4, l = lane & 15;
  const int lw = l & 7;

  int bidx = (int)blockIdx.x;
  const int batch = bidx & 3;
  int j = 287 - (bidx >> 2);
  int g = 0;
  while (j >= 4 * (g + 1) * (g + 2)) ++g;        // g in 0..7
  int j2 = j - 4 * g * (g + 1);
  int tq = j2 / (g + 1);
  int s = j2 - tq * (g + 1);
  const int q0b = (8 * g + tq) * 64;
  const int kvstart = s * 512;
  const int kvend = min(kvstart + 512, q0b + 64);
  const int q0w = q0b + wid * 16;

  const ushort* kbB = kb + (size_t)batch * 262144;
  const ushort* vtB = vt + (size_t)batch * 262144;

  const ushort* qrow = qb + ((size_t)(batch * 4096 + q0w + l)) * 64 + qd * 8;
  short8 Qf0 = *(const short8*)(qrow);
  short8 Qf1 = *(const short8*)(qrow + 32);

  const f32x4 Zc = (f32x4){0.f, 0.f, 0.f, 0.f};
  f32x4 Oc[4] = {Zc, Zc, Zc, Zc};
  f32x4 Lacc = Zc;
  short8 onesf;
  #pragma unroll
  for (int i = 0; i < 8; ++i) onesf[i] = (short)0x3F80;   // bf16 1.0

  ushort* pw = &pbuf[wid][0];
  ushort* pwr = pw + qd * 160 + l;
  const ushort* prd = pw + l * 40 + qd * 8;

#define STAGE(BB, KVC) do{                                                     \
    int r8_ = lane >> 3, sw_ = ((lane & 7) ^ r8_) << 3;                        \
    int rA_ = wid * 8 + r8_;                                                   \
    const ushort* gk_ = kbB + (size_t)((KVC) + rA_) * 64 + sw_;                \
    gl_lds16(gk_,            &Ks[BB][wid * 512]);                              \
    gl_lds16(gk_ + 32 * 64,  &Ks[BB][2048 + wid * 512]);                       \
    const ushort* gv_ = vtB + (size_t)rA_ * 4096 + (KVC) + sw_;                \
    gl_lds16(gv_,              &Vs[BB][wid * 512]);                            \
    gl_lds16(gv_ + 32 * 4096,  &Vs[BB][2048 + wid * 512]);                     \
  } while (0)

#define CHUNK(BB, ROFF, KVG) do{                                               \
    if ((KVG) < q0w + 16){                                                     \
      const ushort* KsB_ = &Ks[BB][0];                                         \
      const ushort* VsB_ = &Vs[BB][0];                                         \
      short8 k0_ = *(const short8*)(KsB_ + (l + (ROFF)) * 64 + ((qd ^ lw) << 3));        \
      short8 k1_ = *(const short8*)(KsB_ + (l + (ROFF)) * 64 + (((qd + 4) ^ lw) << 3));  \
      short8 k2_ = *(const short8*)(KsB_ + (l + 16 + (ROFF)) * 64 + ((qd ^ lw) << 3));   \
      short8 k3_ = *(const short8*)(KsB_ + (l + 16 + (ROFF)) * 64 + (((qd + 4) ^ lw) << 3)); \
      f32x4 s0_ = MFMA16x16x32(Qf0, k0_, Zc);                                  \
      s0_ = MFMA16x16x32(Qf1, k1_, s0_);                                       \
      f32x4 s1_ = MFMA16x16x32(Qf0, k2_, Zc);                                  \
      s1_ = MFMA16x16x32(Qf1, k3_, s1_);                                       \
      float p0_[4], p1_[4];                                                    \
      _Pragma("unroll")                                                        \
      for (int r = 0; r < 4; ++r){                                             \
        p0_[r] = fast_exp2(s0_[r] * K1);                                       \
        p1_[r] = fast_exp2(s1_[r] * K1);                                       \
      }                                                                        \
      if ((KVG) + 31 > q0w){                                                   \
        _Pragma("unroll")                                                      \
        for (int r = 0; r < 4; ++r){                                           \
          int q_ = q0w + qd * 4 + r;                                           \
          if ((KVG) + l > q_) p0_[r] = 0.f;                                    \
          if ((KVG) + 16 + l > q_) p1_[r] = 0.f;                               \
        }                                                                      \
      }                                                                        \
      _Pragma("unroll")                                                        \
      for (int r = 0; r < 4; ++r){                                             \
        pwr[r * 40] = bf16u(p0_[r]);                                           \
        pwr[r * 40 + 16] = bf16u(p1_[r]);                                      \
      }                                                                        \
      short8 Pf_ = *(const short8*)(prd);                                      \
      int vs_ = ((qd + ((ROFF) >> 3)) ^ lw) << 3;                              \
      short8 v0_ = *(const short8*)(VsB_ + (l     ) * 64 + vs_);               \
      short8 v1_ = *(const short8*)(VsB_ + (l + 16) * 64 + vs_);               \
      short8 v2_ = *(const short8*)(VsB_ + (l + 32) * 64 + vs_);               \
      short8 v3_ = *(const short8*)(VsB_ + (l + 48) * 64 + vs_);               \
      Lacc = MFMA16x16x32(Pf_, onesf, Lacc);                                   \
      Oc[0] = MFMA16x16x32(Pf_, v0_, Oc[0]);                                   \
      Oc[1] = MFMA16x16x32(Pf_, v1_, Oc[1]);                                   \
      Oc[2] = MFMA16x16x32(Pf_, v2_, Oc[2]);                                   \
      Oc[3] = MFMA16x16x32(Pf_, v3_, Oc[3]);                                   \
    }                                                                          \
  } while (0)

  const int nst = (kvend - kvstart) >> 6;     // 64-kv stages (1..8)
  STAGE(0, kvstart);
  __syncthreads();
  int kvc = kvstart;
  for (int it = 0; it < nst; ++it){
    int bb = it & 1;
    if (it + 1 < nst) STAGE(bb ^ 1, kvc + 64);   // async prefetch
    CHUNK(bb, 0, kvc);
    CHUNK(bb, 32, kvc + 32);
    __syncthreads();
    kvc += 64;
  }
#undef STAGE
#undef CHUNK

  float* ob = out + ((size_t)(batch * 4096 + q0w + qd * 4)) * 64 + l;
  #pragma unroll
  for (int nf = 0; nf < 4; ++nf)
    #pragma unroll
    for (int r = 0; r < 4; ++r)
      atomicAdd(&ob[(size_t)r * 64 + nf * 16], Oc[nf][r]);
  if (l == 0){
    float* lb = Lbuf + batch * 4096 + q0w + qd * 4;
    #pragma unroll
    for (int r = 0; r < 4; ++r) atomicAdd(&lb[r], Lacc[r]);
  }
}

// ---------------------------------------------------------------------------
// Kernel 3: out[row][d] /= L[row].
// ---------------------------------------------------------------------------
__global__ __launch_bounds__(256) void normalize(
    float* __restrict__ out, const float* __restrict__ Lbuf)
{
  int idx = blockIdx.x * 256 + threadIdx.x;
  f32x4 v = ((f32x4*)out)[idx];
  float inv = fast_rcp(Lbuf[idx >> 4]);
  v[0] *= inv; v[1] *= inv; v[2] *= inv; v[3] *= inv;
  ((f32x4*)out)[idx] = v;
}

// ---------------------------------------------------------------------------
extern "C" void kernel_launch(void* const* d_in, const int* in_sizes, int n_in,
                              void* d_out, int out_size, void* d_ws, size_t ws_size,
                              hipStream_t stream)
{
  const float* Q  = (const float*)d_in[0];
  const float* K  = (const float*)d_in[1];
  const float* V  = (const float*)d_in[2];
  const float* Wq = (const float*)d_in[3];
  const float* bq = (const float*)d_in[4];
  const float* Wk = (const float*)d_in[5];
  const float* bk = (const float*)d_in[6];
  const float* Wv = (const float*)d_in[7];
  const float* bv = (const float*)d_in[8];
  float* out = (float*)d_out;

  // workspace: qb(2MB) kb(2MB) vt(2MB) Wp(384KB) L(64KB)
  unsigned short* qb   = (unsigned short*)d_ws;
  unsigned short* kbuf = qb + (size_t)16384 * 64;
  unsigned short* vtp  = kbuf + (size_t)16384 * 64;
  unsigned short* Wp   = vtp + (size_t)16384 * 64;
  float* Lbuf = (float*)(Wp + (size_t)3 * 65536);

  pack_w<<<256, 256, 0, stream>>>(Wq, Wk, Wv, Wp, out, Lbuf);
  proj_gemm<<<dim3(256, 3), 256, 0, stream>>>(Q, K, V, bq, bk, bv, Wp, qb, kbuf, vtp);
  flash_split<<<1152, 256, 0, stream>>>(qb, kbuf, vtp, out, Lbuf);
  normalize<<<1024, 256, 0, stream>>>(out, Lbuf);
}

// Round 5
// 256.956 us; speedup vs baseline: 1.0211x; 1.0211x over previous
//
#include <hip/hip_runtime.h>
#include <hip/hip_bf16.h>
#include <cstdint>
#include <cstddef>

// B=4, T=4096, C=1024, d=64 causal self-attention head.
// R5: proj_gemm rebuilt for DRAM-sequential access: block = 16 rows,
// 4 waves split-K (256 cols each), staging = 16 contiguous-1KB
// global_load_lds per wave (XOR-swizzled chunk index), ONE barrier,
// compute from private LDS, cross-wave LDS reduction.
// flash unchanged from R3/R4.

typedef __attribute__((ext_vector_type(8))) short short8;       // 8 x bf16 frag
typedef __attribute__((ext_vector_type(4))) float f32x4;
typedef __attribute__((ext_vector_type(4))) unsigned int uint4v;
typedef __attribute__((ext_vector_type(4))) unsigned short ushort4v;
typedef unsigned short ushort;

#define MFMA16x16x32(A,B,C) __builtin_amdgcn_mfma_f32_16x16x32_bf16((A),(B),(C),0,0,0)

static __device__ __forceinline__ unsigned pack2_bf16(float f0, float f1){
  unsigned u0 = __builtin_bit_cast(unsigned, f0) + 0x8000u;
  unsigned u1 = __builtin_bit_cast(unsigned, f1) + 0x8000u;
  return __builtin_amdgcn_perm(u1, u0, 0x07060302u);
}
static __device__ __forceinline__ unsigned short bf16u(float f){
  return (unsigned short)((__builtin_bit_cast(unsigned, f) + 0x8000u) >> 16);
}
static __device__ __forceinline__ short8 cvt8(f32x4 a, f32x4 b){
  union { unsigned u[4]; short8 s; } r;
  r.u[0] = pack2_bf16(a[0], a[1]);
  r.u[1] = pack2_bf16(a[2], a[3]);
  r.u[2] = pack2_bf16(b[0], b[1]);
  r.u[3] = pack2_bf16(b[2], b[3]);
  return r.s;
}
static __device__ __forceinline__ float fast_exp2(float x){
  float r; asm("v_exp_f32 %0, %1" : "=v"(r) : "v"(x)); return r;
}
static __device__ __forceinline__ float fast_rcp(float x){
  float r; asm("v_rcp_f32 %0, %1" : "=v"(r) : "v"(x)); return r;
}
static __device__ __forceinline__ void gl_lds16(const void* g, void* l){
  __builtin_amdgcn_global_load_lds(
      (const __attribute__((address_space(1))) void*)g,
      (__attribute__((address_space(3))) void*)l, 16, 0, 0);
}

// ---------------------------------------------------------------------------
// Kernel 0: pack W fp32 -> bf16 B-fragment layout; also zero out (4MB) + L.
// Wp[p][cc][nf][lane][8]: elem j = W[cc*32+qd*8+j][nf*16+l], lane=(qd,l)
// ---------------------------------------------------------------------------
__global__ __launch_bounds__(256) void pack_w(
    const float* __restrict__ Wq, const float* __restrict__ Wk,
    const float* __restrict__ Wv, unsigned short* __restrict__ Wp,
    float* __restrict__ out, float* __restrict__ Lbuf)
{
  int t = blockIdx.x * 256 + threadIdx.x;      // 256 blocks x 256 = 65536 thr
  if (t < 24576){                               // 3*32*4*64 pack jobs
    int lane = t & 63, nf = (t >> 6) & 3, cc = (t >> 8) & 31, p = t >> 13;
    int qd = lane >> 4, l = lane & 15;
    const float* W = (p == 0) ? Wq : ((p == 1) ? Wk : Wv);
    const float* src = W + (size_t)(cc * 32 + qd * 8) * 64 + nf * 16 + l;
    uint4v u;
    #pragma unroll
    for (int j = 0; j < 4; ++j)
      u[j] = pack2_bf16(src[(2 * j) * 64], src[(2 * j + 1) * 64]);
    *(uint4v*)(Wp + (size_t)t * 8) = u;
  }
  const f32x4 z = (f32x4){0.f, 0.f, 0.f, 0.f};
  f32x4* o4 = (f32x4*)out;
  f32x4* l4 = (f32x4*)Lbuf;
  for (int i = t; i < 262144 + 4096; i += 65536){
    if (i < 262144) o4[i] = z;
    else l4[i - 262144] = z;
  }
}

// ---------------------------------------------------------------------------
// Kernel 1: projections, split-K. grid (1024, 3), block 256 = 4 waves.
// Block = 16 output rows. Wave w: K-slice cols [w*256, w*256+256).
// Stage: per row r (16 rows), one gl_lds = 1 KB CONTIGUOUS global run;
// lane i fetches 16B chunk (i ^ (r&7)) -> LDS slot i (bank-safe reads).
// One barrier after the 64 KB block burst; compute from private LDS;
// partial f32 accs reduced across waves via LDS.
// ---------------------------------------------------------------------------
__global__ __launch_bounds__(256) void proj_gemm(
    const float* __restrict__ Qx, const float* __restrict__ Kx, const float* __restrict__ Vx,
    const float* __restrict__ bqp, const float* __restrict__ bkp, const float* __restrict__ bvp,
    const unsigned short* __restrict__ Wp,
    unsigned short* __restrict__ qb, unsigned short* __restrict__ kb,
    unsigned short* __restrict__ vt)
{
  __shared__ float Xs[4][4096];                 // 64 KB, wave-private 16 KB
  const int tid = threadIdx.x;
  const int lane = tid & 63, wid = tid >> 6;
  const int qd = lane >> 4, l = lane & 15;
  const int p = blockIdx.y;
  const float* X = (p == 0) ? Qx : ((p == 1) ? Kx : Vx);
  const float* bias = (p == 0) ? bqp : ((p == 1) ? bkp : bvp);
  const ushort* W = Wp + (size_t)p * 65536;

  const int rowg = blockIdx.x * 16;
  float* xw = &Xs[wid][0];

  // burst-stage 16 rows x 1 KB (wave's K-slice), swizzled chunk index
  {
    const float* gbase = X + (size_t)rowg * 1024 + wid * 256;
    #pragma unroll
    for (int r = 0; r < 16; ++r){
      const float* g = gbase + (size_t)r * 1024 + ((lane ^ (r & 7)) << 2);
      gl_lds16(g, xw + r * 256);
    }
  }
  __syncthreads();                              // single drain per block

  f32x4 acc[4];
  #pragma unroll
  for (int nf = 0; nf < 4; ++nf) acc[nf] = (f32x4){0.f, 0.f, 0.f, 0.f};

  const float* xrow = xw + l * 256;
  const ushort* wbase = W + (size_t)(wid * 8) * 2048 + lane * 8;
  #pragma unroll
  for (int kc = 0; kc < 8; ++kc){
    int c0 = kc * 8 + qd * 2;
    f32x4 al = *(const f32x4*)(xrow + ((c0 ^ (l & 7)) << 2));
    f32x4 ah = *(const f32x4*)(xrow + (((c0 + 1) ^ (l & 7)) << 2));
    const ushort* wc = wbase + (size_t)kc * 2048;
    short8 b0 = *(const short8*)(wc);
    short8 b1 = *(const short8*)(wc + 512);
    short8 b2 = *(const short8*)(wc + 1024);
    short8 b3 = *(const short8*)(wc + 1536);
    short8 a = cvt8(al, ah);
    acc[0] = MFMA16x16x32(a, b0, acc[0]);
    acc[1] = MFMA16x16x32(a, b1, acc[1]);
    acc[2] = MFMA16x16x32(a, b2, acc[2]);
    acc[3] = MFMA16x16x32(a, b3, acc[3]);
  }

  // partials -> own LDS region (16 x 64 f32)
  #pragma unroll
  for (int nf = 0; nf < 4; ++nf)
    #pragma unroll
    for (int r = 0; r < 4; ++r)
      xw[(qd * 4 + r) * 64 + nf * 16 + l] = acc[nf][r];
  __syncthreads();

  // cross-wave reduce + bias + bf16 + store
  if (p == 2){
    int col = tid & 63, r0 = (tid >> 6) << 2;
    float bb = bias[col];
    ushort4v pk;
    #pragma unroll
    for (int r = 0; r < 4; ++r){
      int o = (r0 + r) * 64 + col;
      float s = Xs[0][o] + Xs[1][o] + Xs[2][o] + Xs[3][o];
      pk[r] = bf16u(s + bb);
    }
    int b = rowg >> 12, tl = rowg & 4095;
    *(ushort4v*)(vt + ((size_t)b * 64 + col) * 4096 + tl + r0) = pk;
  } else {
    ushort* o = (p == 0) ? qb : kb;
    int row = tid >> 4, col0 = (tid & 15) << 2;
    ushort4v pk;
    #pragma unroll
    for (int c = 0; c < 4; ++c){
      int off = row * 64 + col0 + c;
      float s = Xs[0][off] + Xs[1][off] + Xs[2][off] + Xs[3][off];
      pk[c] = bf16u(s + bias[col0 + c]);
    }
    *(ushort4v*)(o + (size_t)(rowg + row) * 64 + col0) = pk;
  }
}

// ---------------------------------------------------------------------------
// Kernel 2: split-KV causal flash, block-cooperative LDS staging (as R3).
// ---------------------------------------------------------------------------
#define K1 0.18033688011112042f   // log2(e)/sqrt(64)

__global__ __launch_bounds__(256) void flash_split(
    const ushort* __restrict__ qb, const ushort* __restrict__ kb,
    const ushort* __restrict__ vt, float* __restrict__ out,
    float* __restrict__ Lbuf)
{
  __shared__ ushort Ks[2][4096];      // [buf][kvrow(64) * 64], 8 slots/row, c^(r&7)
  __shared__ ushort Vs[2][4096];      // [buf][d(64) * 64kv], 8 slots/row, c^(d&7)
  __shared__ ushort pbuf[4][16 * 40];

  const int tid = threadIdx.x;
  const int lane = tid & 63, wid = tid >> 6;
  const int qd = lane >> 4, l = lane & 15;
  const int lw = l & 7;

  int bidx = (int)blockIdx.x;
  const int batch = bidx & 3;
  int j = 287 - (bidx >> 2);
  int g = 0;
  while (j >= 4 * (g + 1) * (g + 2)) ++g;        // g in 0..7
  int j2 = j - 4 * g * (g + 1);
  int tq = j2 / (g + 1);
  int s = j2 - tq * (g + 1);
  const int q0b = (8 * g + tq) * 64;
  const int kvstart = s * 512;
  const int kvend = min(kvstart + 512, q0b + 64);
  const int q0w = q0b + wid * 16;

  const ushort* kbB = kb + (size_t)batch * 262144;
  const ushort* vtB = vt + (size_t)batch * 262144;

  const ushort* qrow = qb + ((size_t)(batch * 4096 + q0w + l)) * 64 + qd * 8;
  short8 Qf0 = *(const short8*)(qrow);
  short8 Qf1 = *(const short8*)(qrow + 32);

  const f32x4 Zc = (f32x4){0.f, 0.f, 0.f, 0.f};
  f32x4 Oc[4] = {Zc, Zc, Zc, Zc};
  f32x4 Lacc = Zc;
  short8 onesf;
  #pragma unroll
  for (int i = 0; i < 8; ++i) onesf[i] = (short)0x3F80;   // bf16 1.0

  ushort* pw = &pbuf[wid][0];
  ushort* pwr = pw + qd * 160 + l;
  const ushort* prd = pw + l * 40 + qd * 8;

#define STAGE(BB, KVC) do{                                                     \
    int r8_ = lane >> 3, sw_ = ((lane & 7) ^ r8_) << 3;                        \
    int rA_ = wid * 8 + r8_;                                                   \
    const ushort* gk_ = kbB + (size_t)((KVC) + rA_) * 64 + sw_;                \
    gl_lds16(gk_,            &Ks[BB][wid * 512]);                              \
    gl_lds16(gk_ + 32 * 64,  &Ks[BB][2048 + wid * 512]);                       \
    const ushort* gv_ = vtB + (size_t)rA_ * 4096 + (KVC) + sw_;                \
    gl_lds16(gv_,              &Vs[BB][wid * 512]);                            \
    gl_lds16(gv_ + 32 * 4096,  &Vs[BB][2048 + wid * 512]);                     \
  } while (0)

#define CHUNK(BB, ROFF, KVG) do{                                               \
    if ((KVG) < q0w + 16){                                                     \
      const ushort* KsB_ = &Ks[BB][0];                                         \
      const ushort* VsB_ = &Vs[BB][0];                                         \
      short8 k0_ = *(const short8*)(KsB_ + (l + (ROFF)) * 64 + ((qd ^ lw) << 3));        \
      short8 k1_ = *(const short8*)(KsB_ + (l + (ROFF)) * 64 + (((qd + 4) ^ lw) << 3));  \
      short8 k2_ = *(const short8*)(KsB_ + (l + 16 + (ROFF)) * 64 + ((qd ^ lw) << 3));   \
      short8 k3_ = *(const short8*)(KsB_ + (l + 16 + (ROFF)) * 64 + (((qd + 4) ^ lw) << 3)); \
      f32x4 s0_ = MFMA16x16x32(Qf0, k0_, Zc);                                  \
      s0_ = MFMA16x16x32(Qf1, k1_, s0_);                                       \
      f32x4 s1_ = MFMA16x16x32(Qf0, k2_, Zc);                                  \
      s1_ = MFMA16x16x32(Qf1, k3_, s1_);                                       \
      float p0_[4], p1_[4];                                                    \
      _Pragma("unroll")                                                        \
      for (int r = 0; r < 4; ++r){                                             \
        p0_[r] = fast_exp2(s0_[r] * K1);                                       \
        p1_[r] = fast_exp2(s1_[r] * K1);                                       \
      }                                                                        \
      if ((KVG) + 31 > q0w){                                                   \
        _Pragma("unroll")                                                      \
        for (int r = 0; r < 4; ++r){                                           \
          int q_ = q0w + qd * 4 + r;                                           \
          if ((KVG) + l > q_) p0_[r] = 0.f;                                    \
          if ((KVG) + 16 + l > q_) p1_[r] = 0.f;                               \
        }                                                                      \
      }                                                                        \
      _Pragma("unroll")                                                        \
      for (int r = 0; r < 4; ++r){                                             \
        pwr[r * 40] = bf16u(p0_[r]);                                           \
        pwr[r * 40 + 16] = bf16u(p1_[r]);                                      \
      }                                                                        \
      short8 Pf_ = *(const short8*)(prd);                                      \
      int vs_ = ((qd + ((ROFF) >> 3)) ^ lw) << 3;                              \
      short8 v0_ = *(const short8*)(VsB_ + (l     ) * 64 + vs_);               \
      short8 v1_ = *(const short8*)(VsB_ + (l + 16) * 64 + vs_);               \
      short8 v2_ = *(const short8*)(VsB_ + (l + 32) * 64 + vs_);               \
      short8 v3_ = *(const short8*)(VsB_ + (l + 48) * 64 + vs_);               \
      Lacc = MFMA16x16x32(Pf_, onesf, Lacc);                                   \
      Oc[0] = MFMA16x16x32(Pf_, v0_, Oc[0]);                                   \
      Oc[1] = MFMA16x16x32(Pf_, v1_, Oc[1]);                                   \
      Oc[2] = MFMA16x16x32(Pf_, v2_, Oc[2]);                                   \
      Oc[3] = MFMA16x16x32(Pf_, v3_, Oc[3]);                                   \
    }                                                                          \
  } while (0)

  const int nst = (kvend - kvstart) >> 6;     // 64-kv stages (1..8)
  STAGE(0, kvstart);
  __syncthreads();
  int kvc = kvstart;
  for (int it = 0; it < nst; ++it){
    int bb = it & 1;
    if (it + 1 < nst) STAGE(bb ^ 1, kvc + 64);   // async prefetch
    CHUNK(bb, 0, kvc);
    CHUNK(bb, 32, kvc + 32);
    __syncthreads();
    kvc += 64;
  }
#undef STAGE
#undef CHUNK

  float* ob = out + ((size_t)(batch * 4096 + q0w + qd * 4)) * 64 + l;
  #pragma unroll
  for (int nf = 0; nf < 4; ++nf)
    #pragma unroll
    for (int r = 0; r < 4; ++r)
      atomicAdd(&ob[(size_t)r * 64 + nf * 16], Oc[nf][r]);
  if (l == 0){
    float* lb = Lbuf + batch * 4096 + q0w + qd * 4;
    #pragma unroll
    for (int r = 0; r < 4; ++r) atomicAdd(&lb[r], Lacc[r]);
  }
}

// ---------------------------------------------------------------------------
// Kernel 3: out[row][d] /= L[row].
// ---------------------------------------------------------------------------
__global__ __launch_bounds__(256) void normalize(
    float* __restrict__ out, const float* __restrict__ Lbuf)
{
  int idx = blockIdx.x * 256 + threadIdx.x;
  f32x4 v = ((f32x4*)out)[idx];
  float inv = fast_rcp(Lbuf[idx >> 4]);
  v[0] *= inv; v[1] *= inv; v[2] *= inv; v[3] *= inv;
  ((f32x4*)out)[idx] = v;
}

// ---------------------------------------------------------------------------
extern "C" void kernel_launch(void* const* d_in, const int* in_sizes, int n_in,
                              void* d_out, int out_size, void* d_ws, size_t ws_size,
                              hipStream_t stream)
{
  const float* Q  = (const float*)d_in[0];
  const float* K  = (const float*)d_in[1];
  const float* V  = (const float*)d_in[2];
  const float* Wq = (const float*)d_in[3];
  const float* bq = (const float*)d_in[4];
  const float* Wk = (const float*)d_in[5];
  const float* bk = (const float*)d_in[6];
  const float* Wv = (const float*)d_in[7];
  const float* bv = (const float*)d_in[8];
  float* out = (float*)d_out;

  // workspace: qb(2MB) kb(2MB) vt(2MB) Wp(384KB) L(64KB)
  unsigned short* qb   = (unsigned short*)d_ws;
  unsigned short* kbuf = qb + (size_t)16384 * 64;
  unsigned short* vtp  = kbuf + (size_t)16384 * 64;
  unsigned short* Wp   = vtp + (size_t)16384 * 64;
  float* Lbuf = (float*)(Wp + (size_t)3 * 65536);

  pack_w<<<256, 256, 0, stream>>>(Wq, Wk, Wv, Wp, out, Lbuf);
  proj_gemm<<<dim3(1024, 3), 256, 0, stream>>>(Q, K, V, bq, bk, bv, Wp, qb, kbuf, vtp);
  flash_split<<<1152, 256, 0, stream>>>(qb, kbuf, vtp, out, Lbuf);
  normalize<<<1024, 256, 0, stream>>>(out, Lbuf);
}

// Round 6
// 256.420 us; speedup vs baseline: 1.0232x; 1.0021x over previous
//
#include <hip/hip_runtime.h>
#include <hip/hip_bf16.h>
#include <cstdint>
#include <cstddef>

// B=4, T=4096, C=1024, d=64 causal self-attention head.
// R6: proj_gemm = continuous-issue register-pipelined GEMM (no LDS, no
// K-loop barriers): wave = 16 rows x K=1024, prefetch-distance-2 ring in
// VGPRs for X (HBM) and W (L2). 12 waves/CU x ~4KB in flight each keeps
// HBM continuously busy. flash unchanged from R3.

typedef __attribute__((ext_vector_type(8))) short short8;       // 8 x bf16 frag
typedef __attribute__((ext_vector_type(4))) float f32x4;
typedef __attribute__((ext_vector_type(4))) unsigned int uint4v;
typedef __attribute__((ext_vector_type(4))) unsigned short ushort4v;
typedef unsigned short ushort;

#define MFMA16x16x32(A,B,C) __builtin_amdgcn_mfma_f32_16x16x32_bf16((A),(B),(C),0,0,0)

static __device__ __forceinline__ unsigned pack2_bf16(float f0, float f1){
  unsigned u0 = __builtin_bit_cast(unsigned, f0) + 0x8000u;
  unsigned u1 = __builtin_bit_cast(unsigned, f1) + 0x8000u;
  return __builtin_amdgcn_perm(u1, u0, 0x07060302u);
}
static __device__ __forceinline__ unsigned short bf16u(float f){
  return (unsigned short)((__builtin_bit_cast(unsigned, f) + 0x8000u) >> 16);
}
static __device__ __forceinline__ short8 cvt8(f32x4 a, f32x4 b){
  union { unsigned u[4]; short8 s; } r;
  r.u[0] = pack2_bf16(a[0], a[1]);
  r.u[1] = pack2_bf16(a[2], a[3]);
  r.u[2] = pack2_bf16(b[0], b[1]);
  r.u[3] = pack2_bf16(b[2], b[3]);
  return r.s;
}
static __device__ __forceinline__ float fast_exp2(float x){
  float r; asm("v_exp_f32 %0, %1" : "=v"(r) : "v"(x)); return r;
}
static __device__ __forceinline__ float fast_rcp(float x){
  float r; asm("v_rcp_f32 %0, %1" : "=v"(r) : "v"(x)); return r;
}
static __device__ __forceinline__ void gl_lds16(const void* g, void* l){
  __builtin_amdgcn_global_load_lds(
      (const __attribute__((address_space(1))) void*)g,
      (__attribute__((address_space(3))) void*)l, 16, 0, 0);
}

// ---------------------------------------------------------------------------
// Kernel 0: pack W fp32 -> bf16 B-fragment layout; also zero out (4MB) + L.
// Wp[p][cc][nf][lane][8]: elem j = W[cc*32+qd*8+j][nf*16+l], lane=(qd,l)
// ---------------------------------------------------------------------------
__global__ __launch_bounds__(256) void pack_w(
    const float* __restrict__ Wq, const float* __restrict__ Wk,
    const float* __restrict__ Wv, unsigned short* __restrict__ Wp,
    float* __restrict__ out, float* __restrict__ Lbuf)
{
  int t = blockIdx.x * 256 + threadIdx.x;      // 256 blocks x 256 = 65536 thr
  if (t < 24576){                               // 3*32*4*64 pack jobs
    int lane = t & 63, nf = (t >> 6) & 3, cc = (t >> 8) & 31, p = t >> 13;
    int qd = lane >> 4, l = lane & 15;
    const float* W = (p == 0) ? Wq : ((p == 1) ? Wk : Wv);
    const float* src = W + (size_t)(cc * 32 + qd * 8) * 64 + nf * 16 + l;
    uint4v u;
    #pragma unroll
    for (int j = 0; j < 4; ++j)
      u[j] = pack2_bf16(src[(2 * j) * 64], src[(2 * j + 1) * 64]);
    *(uint4v*)(Wp + (size_t)t * 8) = u;
  }
  const f32x4 z = (f32x4){0.f, 0.f, 0.f, 0.f};
  f32x4* o4 = (f32x4*)out;
  f32x4* l4 = (f32x4*)Lbuf;
  for (int i = t; i < 262144 + 4096; i += 65536){
    if (i < 262144) o4[i] = z;
    else l4[i - 262144] = z;
  }
}

// ---------------------------------------------------------------------------
// Kernel 1: projections, register-pipelined. grid (256, 3), block 256.
// Wave = 16 rows x K=1024. Ring of 2 slots, prefetch distance 2:
// compute slot s (cc), then immediately re-issue slot s for cc+2.
// No LDS, no barriers -> loads issue continuously across all 12 waves/CU.
// ---------------------------------------------------------------------------
__global__ __launch_bounds__(256, 4) void proj_gemm(
    const float* __restrict__ Qx, const float* __restrict__ Kx, const float* __restrict__ Vx,
    const float* __restrict__ bqp, const float* __restrict__ bkp, const float* __restrict__ bvp,
    const unsigned short* __restrict__ Wp,
    unsigned short* __restrict__ qb, unsigned short* __restrict__ kb,
    unsigned short* __restrict__ vt)
{
  const int tid = threadIdx.x;
  const int lane = tid & 63, wid = tid >> 6;
  const int qd = lane >> 4, l = lane & 15;
  const int p = blockIdx.y;
  const float* X = (p == 0) ? Qx : ((p == 1) ? Kx : Vx);
  const float* bias = (p == 0) ? bqp : ((p == 1) ? bkp : bvp);

  const int row0 = blockIdx.x * 64 + wid * 16;
  const float* xa = X + (size_t)(row0 + l) * 1024 + qd * 8;   // += 32 per cc
  const ushort* wb = Wp + (size_t)p * 65536 + lane * 8;       // += 2048 per cc

  f32x4 a0[2], a1[2];
  short8 w0[2], w1[2], w2[2], w3[2];
  f32x4 acc[4];
  #pragma unroll
  for (int nf = 0; nf < 4; ++nf) acc[nf] = (f32x4){0.f, 0.f, 0.f, 0.f};

#define LOADX(S, CC) do{                                                       \
    a0[S] = *(const f32x4*)(xa + (CC) * 32);                                   \
    a1[S] = *(const f32x4*)(xa + (CC) * 32 + 4);                               \
  } while (0)
#define LOADW(S, CC) do{                                                       \
    const ushort* wc_ = wb + (size_t)(CC) * 2048;                              \
    w0[S] = *(const short8*)(wc_);                                             \
    w1[S] = *(const short8*)(wc_ + 512);                                       \
    w2[S] = *(const short8*)(wc_ + 1024);                                      \
    w3[S] = *(const short8*)(wc_ + 1536);                                      \
  } while (0)
#define COMPUTE(S) do{                                                         \
    short8 a_ = cvt8(a0[S], a1[S]);                                            \
    acc[0] = MFMA16x16x32(a_, w0[S], acc[0]);                                  \
    acc[1] = MFMA16x16x32(a_, w1[S], acc[1]);                                  \
    acc[2] = MFMA16x16x32(a_, w2[S], acc[2]);                                  \
    acc[3] = MFMA16x16x32(a_, w3[S], acc[3]);                                  \
  } while (0)

  LOADX(0, 0); LOADW(0, 0);
  LOADX(1, 1); LOADW(1, 1);
  #pragma unroll 2
  for (int cc = 0; cc < 30; ++cc){
    int s = cc & 1;
    COMPUTE(s);
    LOADX(s, cc + 2);        // re-issue freed slot: continuous stream
    LOADW(s, cc + 2);
  }
  COMPUTE(0);
  COMPUTE(1);
#undef LOADX
#undef LOADW
#undef COMPUTE

  if (p == 2){
    int tg = row0 + qd * 4;
    int b = tg >> 12, tl = tg & 4095;
    #pragma unroll
    for (int nf = 0; nf < 4; ++nf){
      float bb = bias[nf * 16 + l];
      ushort4v pk;
      #pragma unroll
      for (int r = 0; r < 4; ++r) pk[r] = bf16u(acc[nf][r] + bb);
      *(ushort4v*)(vt + ((size_t)b * 64 + nf * 16 + l) * 4096 + tl) = pk;
    }
  } else {
    ushort* o = (p == 0) ? qb : kb;
    #pragma unroll
    for (int nf = 0; nf < 4; ++nf){
      float bb = bias[nf * 16 + l];
      #pragma unroll
      for (int r = 0; r < 4; ++r){
        int row = row0 + qd * 4 + r;
        o[(size_t)row * 64 + nf * 16 + l] = bf16u(acc[nf][r] + bb);
      }
    }
  }
}

// ---------------------------------------------------------------------------
// Kernel 2: split-KV causal flash, block-cooperative LDS staging (as R3).
// ---------------------------------------------------------------------------
#define K1 0.18033688011112042f   // log2(e)/sqrt(64)

__global__ __launch_bounds__(256) void flash_split(
    const ushort* __restrict__ qb, const ushort* __restrict__ kb,
    const ushort* __restrict__ vt, float* __restrict__ out,
    float* __restrict__ Lbuf)
{
  __shared__ ushort Ks[2][4096];      // [buf][kvrow(64) * 64], 8 slots/row, c^(r&7)
  __shared__ ushort Vs[2][4096];      // [buf][d(64) * 64kv], 8 slots/row, c^(d&7)
  __shared__ ushort pbuf[4][16 * 40];

  const int tid = threadIdx.x;
  const int lane = tid & 63, wid = tid >> 6;
  const int qd = lane >> 4, l = lane & 15;
  const int lw = l & 7;

  int bidx = (int)blockIdx.x;
  const int batch = bidx & 3;
  int j = 287 - (bidx >> 2);
  int g = 0;
  while (j >= 4 * (g + 1) * (g + 2)) ++g;        // g in 0..7
  int j2 = j - 4 * g * (g + 1);
  int tq = j2 / (g + 1);
  int s = j2 - tq * (g + 1);
  const int q0b = (8 * g + tq) * 64;
  const int kvstart = s * 512;
  const int kvend = min(kvstart + 512, q0b + 64);
  const int q0w = q0b + wid * 16;

  const ushort* kbB = kb + (size_t)batch * 262144;
  const ushort* vtB = vt + (size_t)batch * 262144;

  const ushort* qrow = qb + ((size_t)(batch * 4096 + q0w + l)) * 64 + qd * 8;
  short8 Qf0 = *(const short8*)(qrow);
  short8 Qf1 = *(const short8*)(qrow + 32);

  const f32x4 Zc = (f32x4){0.f, 0.f, 0.f, 0.f};
  f32x4 Oc[4] = {Zc, Zc, Zc, Zc};
  f32x4 Lacc = Zc;
  short8 onesf;
  #pragma unroll
  for (int i = 0; i < 8; ++i) onesf[i] = (short)0x3F80;   // bf16 1.0

  ushort* pw = &pbuf[wid][0];
  ushort* pwr = pw + qd * 160 + l;
  const ushort* prd = pw + l * 40 + qd * 8;

#define STAGE(BB, KVC) do{                                                     \
    int r8_ = lane >> 3, sw_ = ((lane & 7) ^ r8_) << 3;                        \
    int rA_ = wid * 8 + r8_;                                                   \
    const ushort* gk_ = kbB + (size_t)((KVC) + rA_) * 64 + sw_;                \
    gl_lds16(gk_,            &Ks[BB][wid * 512]);                              \
    gl_lds16(gk_ + 32 * 64,  &Ks[BB][2048 + wid * 512]);                       \
    const ushort* gv_ = vtB + (size_t)rA_ * 4096 + (KVC) + sw_;                \
    gl_lds16(gv_,              &Vs[BB][wid * 512]);                            \
    gl_lds16(gv_ + 32 * 4096,  &Vs[BB][2048 + wid * 512]);                     \
  } while (0)

#define CHUNK(BB, ROFF, KVG) do{                                               \
    if ((KVG) < q0w + 16){                                                     \
      const ushort* KsB_ = &Ks[BB][0];                                         \
      const ushort* VsB_ = &Vs[BB][0];                                         \
      short8 k0_ = *(const short8*)(KsB_ + (l + (ROFF)) * 64 + ((qd ^ lw) << 3));        \
      short8 k1_ = *(const short8*)(KsB_ + (l + (ROFF)) * 64 + (((qd + 4) ^ lw) << 3));  \
      short8 k2_ = *(const short8*)(KsB_ + (l + 16 + (ROFF)) * 64 + ((qd ^ lw) << 3));   \
      short8 k3_ = *(const short8*)(KsB_ + (l + 16 + (ROFF)) * 64 + (((qd + 4) ^ lw) << 3)); \
      f32x4 s0_ = MFMA16x16x32(Qf0, k0_, Zc);                                  \
      s0_ = MFMA16x16x32(Qf1, k1_, s0_);                                       \
      f32x4 s1_ = MFMA16x16x32(Qf0, k2_, Zc);                                  \
      s1_ = MFMA16x16x32(Qf1, k3_, s1_);                                       \
      float p0_[4], p1_[4];                                                    \
      _Pragma("unroll")                                                        \
      for (int r = 0; r < 4; ++r){                                             \
        p0_[r] = fast_exp2(s0_[r] * K1);                                       \
        p1_[r] = fast_exp2(s1_[r] * K1);                                       \
      }                                                                        \
      if ((KVG) + 31 > q0w){                                                   \
        _Pragma("unroll")                                                      \
        for (int r = 0; r < 4; ++r){                                           \
          int q_ = q0w + qd * 4 + r;                                           \
          if ((KVG) + l > q_) p0_[r] = 0.f;                                    \
          if ((KVG) + 16 + l > q_) p1_[r] = 0.f;                               \
        }                                                                      \
      }                                                                        \
      _Pragma("unroll")                                                        \
      for (int r = 0; r < 4; ++r){                                             \
        pwr[r * 40] = bf16u(p0_[r]);                                           \
        pwr[r * 40 + 16] = bf16u(p1_[r]);                                      \
      }                                                                        \
      short8 Pf_ = *(const short8*)(prd);                                      \
      int vs_ = ((qd + ((ROFF) >> 3)) ^ lw) << 3;                              \
      short8 v0_ = *(const short8*)(VsB_ + (l     ) * 64 + vs_);               \
      short8 v1_ = *(const short8*)(VsB_ + (l + 16) * 64 + vs_);               \
      short8 v2_ = *(const short8*)(VsB_ + (l + 32) * 64 + vs_);               \
      short8 v3_ = *(const short8*)(VsB_ + (l + 48) * 64 + vs_);               \
      Lacc = MFMA16x16x32(Pf_, onesf, Lacc);                                   \
      Oc[0] = MFMA16x16x32(Pf_, v0_, Oc[0]);                                   \
      Oc[1] = MFMA16x16x32(Pf_, v1_, Oc[1]);                                   \
      Oc[2] = MFMA16x16x32(Pf_, v2_, Oc[2]);                                   \
      Oc[3] = MFMA16x16x32(Pf_, v3_, Oc[3]);                                   \
    }                                                                          \
  } while (0)

  const int nst = (kvend - kvstart) >> 6;     // 64-kv stages (1..8)
  STAGE(0, kvstart);
  __syncthreads();
  int kvc = kvstart;
  for (int it = 0; it < nst; ++it){
    int bb = it & 1;
    if (it + 1 < nst) STAGE(bb ^ 1, kvc + 64);   // async prefetch
    CHUNK(bb, 0, kvc);
    CHUNK(bb, 32, kvc + 32);
    __syncthreads();
    kvc += 64;
  }
#undef STAGE
#undef CHUNK

  float* ob = out + ((size_t)(batch * 4096 + q0w + qd * 4)) * 64 + l;
  #pragma unroll
  for (int nf = 0; nf < 4; ++nf)
    #pragma unroll
    for (int r = 0; r < 4; ++r)
      atomicAdd(&ob[(size_t)r * 64 + nf * 16], Oc[nf][r]);
  if (l == 0){
    float* lb = Lbuf + batch * 4096 + q0w + qd * 4;
    #pragma unroll
    for (int r = 0; r < 4; ++r) atomicAdd(&lb[r], Lacc[r]);
  }
}

// ---------------------------------------------------------------------------
// Kernel 3: out[row][d] /= L[row].
// ---------------------------------------------------------------------------
__global__ __launch_bounds__(256) void normalize(
    float* __restrict__ out, const float* __restrict__ Lbuf)
{
  int idx = blockIdx.x * 256 + threadIdx.x;
  f32x4 v = ((f32x4*)out)[idx];
  float inv = fast_rcp(Lbuf[idx >> 4]);
  v[0] *= inv; v[1] *= inv; v[2] *= inv; v[3] *= inv;
  ((f32x4*)out)[idx] = v;
}

// ---------------------------------------------------------------------------
extern "C" void kernel_launch(void* const* d_in, const int* in_sizes, int n_in,
                              void* d_out, int out_size, void* d_ws, size_t ws_size,
                              hipStream_t stream)
{
  const float* Q  = (const float*)d_in[0];
  const float* K  = (const float*)d_in[1];
  const float* V  = (const float*)d_in[2];
  const float* Wq = (const float*)d_in[3];
  const float* bq = (const float*)d_in[4];
  const float* Wk = (const float*)d_in[5];
  const float* bk = (const float*)d_in[6];
  const float* Wv = (const float*)d_in[7];
  const float* bv = (const float*)d_in[8];
  float* out = (float*)d_out;

  // workspace: qb(2MB) kb(2MB) vt(2MB) Wp(384KB) L(64KB)
  unsigned short* qb   = (unsigned short*)d_ws;
  unsigned short* kbuf = qb + (size_t)16384 * 64;
  unsigned short* vtp  = kbuf + (size_t)16384 * 64;
  unsigned short* Wp   = vtp + (size_t)16384 * 64;
  float* Lbuf = (float*)(Wp + (size_t)3 * 65536);

  pack_w<<<256, 256, 0, stream>>>(Wq, Wk, Wv, Wp, out, Lbuf);
  proj_gemm<<<dim3(256, 3), 256, 0, stream>>>(Q, K, V, bq, bk, bv, Wp, qb, kbuf, vtp);
  flash_split<<<1152, 256, 0, stream>>>(qb, kbuf, vtp, out, Lbuf);
  normalize<<<1024, 256, 0, stream>>>(out, Lbuf);
}